// Round 10
// baseline (243.480 us; speedup 1.0000x reference)
//
#include <hip/hip_runtime.h>
#include <math.h>

#define BB 1024
#define NN 1024
#define DD 64
#define MARGIN_V 0.5f
#define EPS_V 1e-6f
#define QSPLIT 4               // blocks per batch row in k_dist
#define QCOLS (NN / QSPLIT)    // 256 columns per block (64 per wave)
#define NCHUNK 16              // chunks per wave; 4 columns (1KB/array) each

typedef float f32x4 __attribute__((ext_vector_type(4)));
typedef __attribute__((address_space(1))) const unsigned char glb_u8;
typedef __attribute__((address_space(3))) unsigned char lds_u8;

// ---------------------------------------------------------------------------
// Kernel 1: 4096 blocks = 4 per batch row; 4 waves/block, each wave owns 64
// columns and runs an INDEPENDENT global_load_lds DMA pipeline (no barriers
// in the loop). Per chunk (4 cols): 3 DMA calls (a/p/g, 1KB contiguous each,
// dst = wave-uniform LDS base + lane*16). Schedule per T3/T4: issue chunk
// k+2, then s_waitcnt vmcnt(6) -- counted, never 0 mid-loop -- so 6KB/wave
// stays in flight across every consume. This moves the load return path
// from VGPRs (R1-R9: pinned at 3.9 TB/s delivered, suspected per-CU
// L1-miss-queue cap) to the LDS DMA path.
// Consume: group g of 16 lanes reads col g of the chunk (ds_read_b128),
// 4-step shfl reduce, owner lane gl==chunk updates loss/argmax (verified
// R6 machinery), final 64-lane wave reduce + 4-wave LDS merge.
// ---------------------------------------------------------------------------
__global__ __launch_bounds__(256) void k_dist(const float* __restrict__ a,
                                              const float* __restrict__ p,
                                              const float* __restrict__ g,
                                              float* __restrict__ ws_loss,
                                              float* __restrict__ ws_score,
                                              int* __restrict__ ws_idx,
                                              int* __restrict__ ws_valid)
{
    __shared__ __align__(16) unsigned char smem[4][4][3][1024]; // [wave][buf][arr][1KB] = 48KB

    const int blk  = blockIdx.x;       // 0..4095
    const int b    = blk >> 2;
    const int q    = blk & 3;
    const int tid  = threadIdx.x;
    const int lane = tid & 63;
    const int wave = tid >> 6;         // 0..3
    const int grp  = lane >> 4;        // 0..3
    const int gl   = lane & 15;        // lane within 16-lane group

    const int wcol0 = q * QCOLS + wave * 64;   // wave's columns [wcol0, wcol0+64)
    // per-lane global byte base: column block start + lane*16 (1KB contiguous/wave)
    const size_t baseByte = ((size_t)b * NN * DD + (size_t)wcol0 * DD) * 4u + (size_t)lane * 16u;
    const unsigned char* aB = (const unsigned char*)a + baseByte;
    const unsigned char* pB = (const unsigned char*)p + baseByte;
    const unsigned char* gB = (const unsigned char*)g + baseByte;

    float loss_acc   = 0.f;
    float best_score = -INFINITY;
    int   best_idx   = 0x7fffffff;

    // --- stage chunk ch (cols [wcol0+ch*4, +4)) into buffer buf: 3 DMA calls ---
    auto STAGE = [&](int ch, int buf) {
        const size_t o = (size_t)ch * 1024u;
        __builtin_amdgcn_global_load_lds((glb_u8*)(aB + o), (lds_u8*)&smem[wave][buf][0][0], 16, 0, 0);
        __builtin_amdgcn_global_load_lds((glb_u8*)(pB + o), (lds_u8*)&smem[wave][buf][1][0], 16, 0, 0);
        __builtin_amdgcn_global_load_lds((glb_u8*)(gB + o), (lds_u8*)&smem[wave][buf][2][0], 16, 0, 0);
    };

    // --- consume chunk ch from buffer buf: group grp owns col (ch*4 + grp) ---
    auto CONSUME = [&](int ch, int buf) {
        const int off = grp * 256 + gl * 16;
        const f32x4 va = *(const f32x4*)&smem[wave][buf][0][off];
        const f32x4 vp = *(const f32x4*)&smem[wave][buf][1][off];
        const f32x4 vg = *(const f32x4*)&smem[wave][buf][2][off];
        float sp = 0.f, sn = 0.f, t;
        #pragma unroll
        for (int e = 0; e < 4; ++e) {
            t = va[e] - vp[e] + EPS_V; sp += t * t;
            t = va[e] - vg[e] + EPS_V; sn += t * t;
        }
        #pragma unroll
        for (int m = 1; m < 16; m <<= 1) {
            sp += __shfl_xor(sp, m, 64);
            sn += __shfl_xor(sn, m, 64);
        }
        if (gl == ch) {                       // unique owner lane per (chunk, group)
            const int n = wcol0 + ch * 4 + grp;
            const float diff = MARGIN_V + sqrtf(sp) - sqrtf(sn);
            loss_acc += fmaxf(diff, 0.f);
            const float sc = (diff > 0.f) ? sqrtf(sn) : -INFINITY;
            if (sc > best_score || (sc == best_score && n < best_idx)) {
                best_score = sc; best_idx = n;
            }
        }
    };

    // prologue: 2 chunks in flight
    STAGE(0, 0);
    STAGE(1, 1);

    #pragma unroll 1
    for (int k = 0; k < NCHUNK - 2; ++k) {
        STAGE(k + 2, (k + 2) & 3);                      // outstanding: k, k+1, k+2 (9 loads)
        asm volatile("s_waitcnt vmcnt(6)" ::: "memory");// oldest 3 (chunk k) landed
        __builtin_amdgcn_sched_barrier(0);
        CONSUME(k, k & 3);
    }
    asm volatile("s_waitcnt vmcnt(3)" ::: "memory");
    __builtin_amdgcn_sched_barrier(0);
    CONSUME(NCHUNK - 2, (NCHUNK - 2) & 3);
    asm volatile("s_waitcnt vmcnt(0)" ::: "memory");
    __builtin_amdgcn_sched_barrier(0);
    CONSUME(NCHUNK - 1, (NCHUNK - 1) & 3);

    // ---- wave reduce: sum(loss), argmax(score) with first-index tie-break ----
    for (int m = 1; m < 64; m <<= 1) {
        loss_acc += __shfl_xor(loss_acc, m, 64);
        const float so = __shfl_xor(best_score, m, 64);
        const int   io = __shfl_xor(best_idx, m, 64);
        if (so > best_score || (so == best_score && io < best_idx)) {
            best_score = so; best_idx = io;
        }
    }

    __shared__ float s_loss[4];
    __shared__ float s_score[4];
    __shared__ int   s_idx[4];
    if ((tid & 63) == 0) {
        s_loss[wave]  = loss_acc;
        s_score[wave] = best_score;
        s_idx[wave]   = best_idx;
    }
    __syncthreads();
    if (tid == 0) {
        float ls = 0.f, bs = -INFINITY;
        int   bi = 0x7fffffff;
        for (int k = 0; k < 4; ++k) {
            ls += s_loss[k];
            const float sc = s_score[k]; const int ix = s_idx[k];
            if (sc > bs || (sc == bs && ix < bi)) { bs = sc; bi = ix; }
        }
        ws_loss[blk]  = ls;
        ws_score[blk] = bs;
        ws_idx[blk]   = bi;
        ws_valid[blk] = (bs > -INFINITY) ? 1 : 0;
    }
}

// ---------------------------------------------------------------------------
// Kernel 2 (single block, 1024 threads): thread b merges its QSPLIT partials
// (first-index tie-break), writes sel/has_valid, block-reduces loss -> mean.
// ---------------------------------------------------------------------------
__global__ __launch_bounds__(1024) void k_merge(const float* __restrict__ ws_loss,
                                                const float* __restrict__ ws_score,
                                                const int* __restrict__ ws_idx,
                                                const int* __restrict__ ws_valid,
                                                float* __restrict__ out_loss,
                                                int* __restrict__ ws_sel,
                                                float* __restrict__ out_hasvalid)
{
    const int b = threadIdx.x;
    float ls = 0.f;
    float bs = -INFINITY;
    int   bi = 0x7fffffff;
    int   av = 0;
    for (int qq = 0; qq < QSPLIT; ++qq) {
        const int idx = b * QSPLIT + qq;
        const float sc = ws_score[idx];
        const int   ix = ws_idx[idx];
        if (sc > bs || (sc == bs && ix < bi)) { bs = sc; bi = ix; }
        ls += ws_loss[idx];
        av |= ws_valid[idx];
    }
    ws_sel[b] = bi;
    out_hasvalid[b] = av ? 1.0f : 0.0f;

    __shared__ float s[16];
    float v = ls;
    for (int m = 1; m < 64; m <<= 1) v += __shfl_xor(v, m, 64);
    if ((b & 63) == 0) s[b >> 6] = v;
    __syncthreads();
    if (b == 0) {
        float tot = 0.f;
        for (int k = 0; k < 16; ++k) tot += s[k];
        out_loss[0] = tot / (float)((size_t)BB * NN);
    }
}

// ---------------------------------------------------------------------------
// Kernel 3: hard_neg[b] = negative[sel_col[b]].  Scalar coalesced copies
// (dst is 4B-misaligned vs 16B). Non-temporal stores: output never re-read.
// ---------------------------------------------------------------------------
__global__ __launch_bounds__(256) void k_gather(const float* __restrict__ g,
                                                const int* __restrict__ ws_sel,
                                                float* __restrict__ out_hn)
{
    const int b   = blockIdx.y;
    const int sel = ws_sel[b];
    const float* __restrict__ src = g      + (size_t)sel * (NN * DD);
    float* __restrict__       dst = out_hn + (size_t)b   * (NN * DD);
    const int t = blockIdx.x * blockDim.x + threadIdx.x;   // 0..8191
    #pragma unroll
    for (int k = 0; k < (NN * DD) / 8192; ++k) {
        const int idx = t + k * 8192;
        __builtin_nontemporal_store(src[idx], dst + idx);
    }
}

extern "C" void kernel_launch(void* const* d_in, const int* in_sizes, int n_in,
                              void* d_out, int out_size, void* d_ws, size_t ws_size,
                              hipStream_t stream) {
    const float* anchor   = (const float*)d_in[0];
    const float* positive = (const float*)d_in[1];
    const float* negative = (const float*)d_in[2];
    float* out = (float*)d_out;

    // out layout: [0] loss | [1 .. 1+B*N*D) hard_neg | [1+B*N*D .. +B) has_valid
    float* out_loss     = out;
    float* out_hard_neg = out + 1;
    float* out_hasvalid = out + 1 + (size_t)BB * NN * DD;

    // ws layout: 4096 loss | 4096 score | 4096 idx | 4096 valid | 1024 sel
    float* ws_loss  = (float*)d_ws;
    float* ws_score = ws_loss + BB * QSPLIT;
    int*   ws_idx   = (int*)(ws_score + BB * QSPLIT);
    int*   ws_valid = ws_idx + BB * QSPLIT;
    int*   ws_sel   = ws_valid + BB * QSPLIT;

    k_dist<<<dim3(BB * QSPLIT), dim3(256), 0, stream>>>(anchor, positive, negative,
                                                        ws_loss, ws_score, ws_idx, ws_valid);
    k_merge<<<dim3(1), dim3(1024), 0, stream>>>(ws_loss, ws_score, ws_idx, ws_valid,
                                                out_loss, ws_sel, out_hasvalid);
    k_gather<<<dim3(32, BB), dim3(256), 0, stream>>>(negative, ws_sel, out_hard_neg);
}